// Round 3
// baseline (358.623 us; speedup 1.0000x reference)
//
#include <hip/hip_runtime.h>
#include <hip/hip_bf16.h>
#include <stdint.h>

#define GAT_ALPHA 0.2f
#define LOG2E 1.4426950408889634f
#define WPITCH 2080   // whT row pitch in shorts: 2048+32 breaks 4KB channel/set aliasing

typedef __attribute__((ext_vector_type(8))) __bf16 bf16x8;
typedef __attribute__((ext_vector_type(4))) float f32x4;

union B8 {
  bf16x8 b;
  unsigned short u[8];
  int4 i4;
};

__device__ __forceinline__ unsigned short f2bf(float f) {
  unsigned int u = __float_as_uint(f);
  u += 0x7fffu + ((u >> 16) & 1u);   // RNE; inputs are finite
  return (unsigned short)(u >> 16);
}

// ---------------- Kernel A: wh = x @ W^T (fp32), emit whT (bf16, o-major), s, d ----
// 32 rows/block, 256 threads. Thread: 4 o's (lane32 + 32m) x 4 rows ((tid/32)*4+r).
// k-loop software-pipelined: xv/wv double-buffered so strided W loads are 1 step ahead.
__global__ __launch_bounds__(256) void gat_wh(
    const float* __restrict__ x, const float* __restrict__ W,
    const float* __restrict__ a, unsigned short* __restrict__ whT,
    float* __restrict__ s_out, float* __restrict__ d_out) {
  __shared__ float X[32][260];
  const int tid = threadIdx.x;
  const int row0 = blockIdx.x * 32;
  {
    const int rr = tid >> 3;
    const int seg = (tid & 7) << 2;
    const float* xrow = x + (size_t)(row0 + rr) * 256;
#pragma unroll
    for (int it = 0; it < 8; ++it) {
      const int k = seg + it * 32;
      *(float4*)(&X[rr][k]) = *(const float4*)(xrow + k);
    }
  }
  __syncthreads();
  const int lane32 = tid & 31;
  const int r0 = (tid >> 5) << 2;
  float acc[4][4];
#pragma unroll
  for (int m = 0; m < 4; ++m)
#pragma unroll
    for (int r = 0; r < 4; ++r) acc[m][r] = 0.f;
  const float* W0 = W + (size_t)lane32 * 256;

  float4 xv[2][4], wv[2][4];
#pragma unroll
  for (int r = 0; r < 4; ++r) xv[0][r] = *(const float4*)(&X[r0 + r][0]);
#pragma unroll
  for (int m = 0; m < 4; ++m) wv[0][m] = *(const float4*)(W0 + m * 8192);
#pragma unroll 2
  for (int k4 = 0; k4 < 64; ++k4) {
    const int cur = k4 & 1, nxt = cur ^ 1;
    if (k4 < 63) {
      const int kn = (k4 + 1) << 2;
#pragma unroll
      for (int r = 0; r < 4; ++r) xv[nxt][r] = *(const float4*)(&X[r0 + r][kn]);
#pragma unroll
      for (int m = 0; m < 4; ++m) wv[nxt][m] = *(const float4*)(W0 + m * 8192 + kn);
    }
#pragma unroll
    for (int m = 0; m < 4; ++m)
#pragma unroll
      for (int r = 0; r < 4; ++r) {
        acc[m][r] = fmaf(wv[cur][m].x, xv[cur][r].x, acc[m][r]);
        acc[m][r] = fmaf(wv[cur][m].y, xv[cur][r].y, acc[m][r]);
        acc[m][r] = fmaf(wv[cur][m].z, xv[cur][r].z, acc[m][r]);
        acc[m][r] = fmaf(wv[cur][m].w, xv[cur][r].w, acc[m][r]);
      }
  }
  float asrc[4], adst[4];
#pragma unroll
  for (int m = 0; m < 4; ++m) {
    asrc[m] = a[lane32 + 32 * m];
    adst[m] = a[128 + lane32 + 32 * m];
  }
  float sp[4], dp[4];
#pragma unroll
  for (int r = 0; r < 4; ++r) {
    sp[r] = acc[0][r] * asrc[0] + acc[1][r] * asrc[1] + acc[2][r] * asrc[2] + acc[3][r] * asrc[3];
    dp[r] = acc[0][r] * adst[0] + acc[1][r] * adst[1] + acc[2][r] * adst[2] + acc[3][r] * adst[3];
  }
#pragma unroll
  for (int off = 16; off >= 1; off >>= 1) {
#pragma unroll
    for (int r = 0; r < 4; ++r) {
      sp[r] += __shfl_xor(sp[r], off, 64);
      dp[r] += __shfl_xor(dp[r], off, 64);
    }
  }
  if (lane32 == 0) {
#pragma unroll
    for (int r = 0; r < 4; ++r) {
      s_out[row0 + r0 + r] = sp[r];
      d_out[row0 + r0 + r] = dp[r];
    }
  }
  const int b = row0 >> 11;
  const int rib = (row0 & 2047) + r0;
#pragma unroll
  for (int m = 0; m < 4; ++m) {
    const int o = lane32 + 32 * m;
    uint2 pk;
    pk.x = (unsigned int)f2bf(acc[m][0]) | ((unsigned int)f2bf(acc[m][1]) << 16);
    pk.y = (unsigned int)f2bf(acc[m][2]) | ((unsigned int)f2bf(acc[m][3]) << 16);
    *(uint2*)(whT + (size_t)(b * 128 + o) * WPITCH + rib) = pk;
  }
}

// ---------------- Kernel B: masked attention via MFMA, j-split 4x, deep prefetch ----
// Block = 256 thr = 4 waves; block owns 16 rows i; wave w handles j in [w*512,(w+1)*512).
// adj: 4-deep register prefetch. V-frags (whT): register double-buffered, 1 chunk ahead.
// No running max needed (e <= ~18 so fp32 exp never overflows) -> linear num/den split.
__global__ __launch_bounds__(256) void gat_attn(
    const int* __restrict__ adj, const unsigned short* __restrict__ whT,
    const float* __restrict__ s, const float* __restrict__ dvec,
    float* __restrict__ out) {
  __shared__ float buf[4][16][132];    // [wave][i][o] fp32 partial num
  __shared__ float denb[64];           // [wave][i] partial den
  __shared__ float dl[2048];           // d for whole batch row-range
  const int tid = threadIdx.x;
  const int wave = tid >> 6;
  const int lane = tid & 63;
  const int il = lane & 15;
  const int quad = lane >> 4;
  const int qo = quad << 3;
  const int blk = blockIdx.x;
  const int b = blk >> 7;
  const int tile = blk & 127;
  const int i = tile * 16 + il;
  const size_t browi = ((size_t)b << 11) + i;
  {
    const float* dsrc = dvec + ((size_t)b << 11);
#pragma unroll
    for (int it = 0; it < 2; ++it) {
      const int idx = it * 1024 + tid * 4;
      *(float4*)(&dl[idx]) = *(const float4*)(dsrc + idx);
    }
  }
  __syncthreads();
  const float sv = s[browi];
  const int jb = wave << 9;
  const int* adjq = adj + browi * 2048 + jb + qo;
  const unsigned short* whTb = whT + (size_t)(b * 128) * WPITCH;
  const unsigned short* wrow[8];
#pragma unroll
  for (int nt = 0; nt < 8; ++nt)
    wrow[nt] = whTb + (size_t)(nt * 16 + il) * WPITCH + jb + qo;

  f32x4 acc[8];
#pragma unroll
  for (int nt = 0; nt < 8; ++nt) acc[nt] = (f32x4){0.f, 0.f, 0.f, 0.f};
  float den = 0.f;

  int4 adjbuf[4][2];            // 4-deep prefetch: 128 cache lines in flight per wave
#pragma unroll
  for (int pp = 0; pp < 4; ++pp) {
    adjbuf[pp][0] = *(const int4*)(adjq + pp * 32);
    adjbuf[pp][1] = *(const int4*)(adjq + pp * 32 + 4);
  }
  B8 af[2][8];                  // V-frag double buffer
#pragma unroll
  for (int nt = 0; nt < 8; ++nt) af[0][nt].i4 = *(const int4*)(wrow[nt]);

#pragma unroll 2
  for (int t = 0; t < 16; ++t) {
    const int cur = t & 1, nxt = cur ^ 1;
    const int j0 = t * 32;
    if (t < 15) {               // prefetch next chunk's V-frags before this chunk's MFMAs
#pragma unroll
      for (int nt = 0; nt < 8; ++nt)
        af[nxt][nt].i4 = *(const int4*)(wrow[nt] + j0 + 32);
    }
    const int4 aj0 = adjbuf[t & 3][0];
    const int4 aj1 = adjbuf[t & 3][1];
    if (t < 12) {
      adjbuf[t & 3][0] = *(const int4*)(adjq + (t + 4) * 32);
      adjbuf[t & 3][1] = *(const int4*)(adjq + (t + 4) * 32 + 4);
    }
    const float4 d0 = *(const float4*)(&dl[jb + qo + j0]);
    const float4 d1 = *(const float4*)(&dl[jb + qo + j0 + 4]);
    const float dd[8] = {d0.x, d0.y, d0.z, d0.w, d1.x, d1.y, d1.z, d1.w};
    const int aj[8] = {aj0.x, aj0.y, aj0.z, aj0.w, aj1.x, aj1.y, aj1.z, aj1.w};
    B8 pf;
#pragma unroll
    for (int u = 0; u < 8; ++u) {
      float e = sv + dd[u];
      e = fmaxf(e, GAT_ALPHA * e);                 // leaky relu
      float p = __builtin_amdgcn_exp2f(e * LOG2E); // no max-sub: e <= ~18
      p = (aj[u] != 0) ? p : 0.f;
      den += p;
      pf.u[u] = f2bf(p);
    }
#pragma unroll
    for (int nt = 0; nt < 8; ++nt)
      acc[nt] = __builtin_amdgcn_mfma_f32_16x16x32_bf16(af[cur][nt].b, pf.b, acc[nt], 0, 0, 0);
  }
  den += __shfl_xor(den, 16, 64);
  den += __shfl_xor(den, 32, 64);
  if (lane < 16) denb[wave * 16 + il] = den;
#pragma unroll
  for (int nt = 0; nt < 8; ++nt)
    *(f32x4*)(&buf[wave][il][nt * 16 + (quad << 2)]) = acc[nt];
  __syncthreads();
  const float dtot = denb[il] + denb[16 + il] + denb[32 + il] + denb[48 + il];
  const float inv = 1.0f / dtot;
  float* op = out + browi * 128;
#pragma unroll
  for (int h = 0; h < 2; ++h) {
    const int nt = wave * 2 + h;
    const int o0 = nt * 16 + (quad << 2);
    f32x4 sum = *(const f32x4*)(&buf[0][il][o0]);
    sum += *(const f32x4*)(&buf[1][il][o0]);
    sum += *(const f32x4*)(&buf[2][il][o0]);
    sum += *(const f32x4*)(&buf[3][il][o0]);
    float4 v;
    v.x = fmaxf(sum[0] * inv, 0.f);
    v.y = fmaxf(sum[1] * inv, 0.f);
    v.z = fmaxf(sum[2] * inv, 0.f);
    v.w = fmaxf(sum[3] * inv, 0.f);
    *(float4*)(op + o0) = v;
  }
}

extern "C" void kernel_launch(void* const* d_in, const int* in_sizes, int n_in,
                              void* d_out, int out_size, void* d_ws, size_t ws_size,
                              hipStream_t stream) {
  const float* x = (const float*)d_in[0];
  const int* adj = (const int*)d_in[1];
  const float* W = (const float*)d_in[2];
  const float* a = (const float*)d_in[3];
  float* out = (float*)d_out;
  // workspace: whT bf16 [8][128][WPITCH] | s fp32 [16384] | d fp32 [16384]
  unsigned short* whT = (unsigned short*)d_ws;
  float* s = (float*)((char*)d_ws + (size_t)8 * 128 * WPITCH * 2);
  float* dv = s + 16384;
  gat_wh<<<512, 256, 0, stream>>>(x, W, a, whT, s, dv);
  gat_attn<<<1024, 256, 0, stream>>>(adj, whT, s, dv, out);
}

// Round 4
// 311.687 us; speedup vs baseline: 1.1506x; 1.1506x over previous
//
#include <hip/hip_runtime.h>
#include <hip/hip_bf16.h>
#include <stdint.h>

#define GAT_ALPHA 0.2f
#define LOG2E 1.4426950408889634f
#define WPITCH 2080   // whT row pitch in shorts: 2048+32 breaks 4KB set/channel aliasing

typedef __attribute__((ext_vector_type(8))) __bf16 bf16x8;
typedef __attribute__((ext_vector_type(4))) float f32x4;

union B8 {
  bf16x8 b;
  unsigned short u[8];
  int4 i4;
};

__device__ __forceinline__ unsigned short f2bf(float f) {
  unsigned int u = __float_as_uint(f);
  u += 0x7fffu + ((u >> 16) & 1u);   // RNE; inputs are finite
  return (unsigned short)(u >> 16);
}

// ---------------- Kernel A: wh = x @ W^T (fp32), emit whT (bf16, o-major), s, d ----
// 32 rows/block, 256 threads. Thread: 4 o's (lane32 + 32m) x 4 rows ((tid/32)*4+r).
// launch_bounds(.,2): allow 256 VGPRs so the pipelined W loads stay register-resident.
__global__ __launch_bounds__(256, 2) void gat_wh(
    const float* __restrict__ x, const float* __restrict__ W,
    const float* __restrict__ a, unsigned short* __restrict__ whT,
    float* __restrict__ s_out, float* __restrict__ d_out) {
  __shared__ float X[32][260];
  const int tid = threadIdx.x;
  const int row0 = blockIdx.x * 32;
  {
    const int rr = tid >> 3;
    const int seg = (tid & 7) << 2;
    const float* xrow = x + (size_t)(row0 + rr) * 256;
#pragma unroll
    for (int it = 0; it < 8; ++it) {
      const int k = seg + it * 32;
      *(float4*)(&X[rr][k]) = *(const float4*)(xrow + k);
    }
  }
  __syncthreads();
  const int lane32 = tid & 31;
  const int r0 = (tid >> 5) << 2;
  float acc[4][4];
#pragma unroll
  for (int m = 0; m < 4; ++m)
#pragma unroll
    for (int r = 0; r < 4; ++r) acc[m][r] = 0.f;
  const float* W0 = W + (size_t)lane32 * 256;

  float4 xv[2][4], wv[2][4];
#pragma unroll
  for (int r = 0; r < 4; ++r) xv[0][r] = *(const float4*)(&X[r0 + r][0]);
#pragma unroll
  for (int m = 0; m < 4; ++m) wv[0][m] = *(const float4*)(W0 + m * 8192);
#pragma unroll
  for (int k4 = 0; k4 < 64; ++k4) {
    const int cur = k4 & 1, nxt = cur ^ 1;
    if (k4 < 63) {
      const int kn = (k4 + 1) << 2;
#pragma unroll
      for (int r = 0; r < 4; ++r) xv[nxt][r] = *(const float4*)(&X[r0 + r][kn]);
#pragma unroll
      for (int m = 0; m < 4; ++m) wv[nxt][m] = *(const float4*)(W0 + m * 8192 + kn);
    }
#pragma unroll
    for (int m = 0; m < 4; ++m)
#pragma unroll
      for (int r = 0; r < 4; ++r) {
        acc[m][r] = fmaf(wv[cur][m].x, xv[cur][r].x, acc[m][r]);
        acc[m][r] = fmaf(wv[cur][m].y, xv[cur][r].y, acc[m][r]);
        acc[m][r] = fmaf(wv[cur][m].z, xv[cur][r].z, acc[m][r]);
        acc[m][r] = fmaf(wv[cur][m].w, xv[cur][r].w, acc[m][r]);
      }
  }
  float asrc[4], adst[4];
#pragma unroll
  for (int m = 0; m < 4; ++m) {
    asrc[m] = a[lane32 + 32 * m];
    adst[m] = a[128 + lane32 + 32 * m];
  }
  float sp[4], dp[4];
#pragma unroll
  for (int r = 0; r < 4; ++r) {
    sp[r] = acc[0][r] * asrc[0] + acc[1][r] * asrc[1] + acc[2][r] * asrc[2] + acc[3][r] * asrc[3];
    dp[r] = acc[0][r] * adst[0] + acc[1][r] * adst[1] + acc[2][r] * adst[2] + acc[3][r] * adst[3];
  }
#pragma unroll
  for (int off = 16; off >= 1; off >>= 1) {
#pragma unroll
    for (int r = 0; r < 4; ++r) {
      sp[r] += __shfl_xor(sp[r], off, 64);
      dp[r] += __shfl_xor(dp[r], off, 64);
    }
  }
  if (lane32 == 0) {
#pragma unroll
    for (int r = 0; r < 4; ++r) {
      s_out[row0 + r0 + r] = sp[r];
      d_out[row0 + r0 + r] = dp[r];
    }
  }
  const int b = row0 >> 11;
  const int rib = (row0 & 2047) + r0;
#pragma unroll
  for (int m = 0; m < 4; ++m) {
    const int o = lane32 + 32 * m;
    uint2 pk;
    pk.x = (unsigned int)f2bf(acc[m][0]) | ((unsigned int)f2bf(acc[m][1]) << 16);
    pk.y = (unsigned int)f2bf(acc[m][2]) | ((unsigned int)f2bf(acc[m][3]) << 16);
    *(uint2*)(whT + (size_t)(b * 128 + o) * WPITCH + rib) = pk;
  }
}

// ---------------- Kernel B: masked attention via MFMA, j-split 4x ------------------
// Block = 256 thr = 4 waves; block owns 16 rows i; wave w handles j in [w*512,(w+1)*512).
// j-loop FULLY unrolled: all prefetch-buffer indices are compile-time constants (the
// R3 spill came from adjbuf[t&3] under partial unroll). launch_bounds(.,2) gives the
// scheduler a 256-VGPR budget to keep all prefetches register-resident (MLP).
// No running max needed (e <= ~18 so fp32 exp never overflows) -> linear num/den split.
__global__ __launch_bounds__(256, 2) void gat_attn(
    const int* __restrict__ adj, const unsigned short* __restrict__ whT,
    const float* __restrict__ s, const float* __restrict__ dvec,
    float* __restrict__ out) {
  __shared__ float buf[4][16][132];    // [wave][i][o] fp32 partial num
  __shared__ float denb[64];           // [wave][i] partial den
  __shared__ float dl[2048];           // d for whole batch
  const int tid = threadIdx.x;
  const int wave = tid >> 6;
  const int lane = tid & 63;
  const int il = lane & 15;
  const int quad = lane >> 4;
  const int qo = quad << 3;
  const int blk = blockIdx.x;
  const int b = blk >> 7;
  const int tile = blk & 127;
  const int i = tile * 16 + il;
  const size_t browi = ((size_t)b << 11) + i;
  {
    const float* dsrc = dvec + ((size_t)b << 11);
#pragma unroll
    for (int it = 0; it < 2; ++it) {
      const int idx = it * 1024 + tid * 4;
      *(float4*)(&dl[idx]) = *(const float4*)(dsrc + idx);
    }
  }
  __syncthreads();
  const float sv = s[browi];
  const int jb = wave << 9;
  const int* adjq = adj + browi * 2048 + jb + qo;
  const unsigned short* whTb = whT + (size_t)(b * 128) * WPITCH;
  const unsigned short* wrow[8];
#pragma unroll
  for (int nt = 0; nt < 8; ++nt)
    wrow[nt] = whTb + (size_t)(nt * 16 + il) * WPITCH + jb + qo;

  f32x4 acc[8];
#pragma unroll
  for (int nt = 0; nt < 8; ++nt) acc[nt] = (f32x4){0.f, 0.f, 0.f, 0.f};
  float den = 0.f;

  int4 adjbuf[4][2];            // 4-deep adj prefetch (constant-indexed under full unroll)
#pragma unroll
  for (int pp = 0; pp < 4; ++pp) {
    adjbuf[pp][0] = *(const int4*)(adjq + pp * 32);
    adjbuf[pp][1] = *(const int4*)(adjq + pp * 32 + 4);
  }
  B8 af[2][8];                  // V-frag double buffer
#pragma unroll
  for (int nt = 0; nt < 8; ++nt) af[0][nt].i4 = *(const int4*)(wrow[nt]);

#pragma unroll                  // FULL unroll: 16 iterations, all indices constant
  for (int t = 0; t < 16; ++t) {
    const int cur = t & 1, nxt = cur ^ 1;
    const int j0 = t * 32;
    if (t < 15) {               // prefetch next chunk's V-frags before this chunk's MFMAs
#pragma unroll
      for (int nt = 0; nt < 8; ++nt)
        af[nxt][nt].i4 = *(const int4*)(wrow[nt] + j0 + 32);
    }
    const int4 aj0 = adjbuf[t & 3][0];
    const int4 aj1 = adjbuf[t & 3][1];
    if (t < 12) {
      adjbuf[t & 3][0] = *(const int4*)(adjq + (t + 4) * 32);
      adjbuf[t & 3][1] = *(const int4*)(adjq + (t + 4) * 32 + 4);
    }
    const float4 d0 = *(const float4*)(&dl[jb + qo + j0]);
    const float4 d1 = *(const float4*)(&dl[jb + qo + j0 + 4]);
    const float dd[8] = {d0.x, d0.y, d0.z, d0.w, d1.x, d1.y, d1.z, d1.w};
    const int aj[8] = {aj0.x, aj0.y, aj0.z, aj0.w, aj1.x, aj1.y, aj1.z, aj1.w};
    B8 pf;
#pragma unroll
    for (int u = 0; u < 8; ++u) {
      float e = sv + dd[u];
      e = fmaxf(e, GAT_ALPHA * e);                 // leaky relu
      float p = __builtin_amdgcn_exp2f(e * LOG2E); // no max-sub: e <= ~18
      p = (aj[u] != 0) ? p : 0.f;
      den += p;
      pf.u[u] = f2bf(p);
    }
#pragma unroll
    for (int nt = 0; nt < 8; ++nt)
      acc[nt] = __builtin_amdgcn_mfma_f32_16x16x32_bf16(af[cur][nt].b, pf.b, acc[nt], 0, 0, 0);
  }
  den += __shfl_xor(den, 16, 64);
  den += __shfl_xor(den, 32, 64);
  if (lane < 16) denb[wave * 16 + il] = den;
#pragma unroll
  for (int nt = 0; nt < 8; ++nt)
    *(f32x4*)(&buf[wave][il][nt * 16 + (quad << 2)]) = acc[nt];
  __syncthreads();
  const float dtot = denb[il] + denb[16 + il] + denb[32 + il] + denb[48 + il];
  const float inv = 1.0f / dtot;
  float* op = out + browi * 128;
#pragma unroll
  for (int h = 0; h < 2; ++h) {
    const int nt = wave * 2 + h;
    const int o0 = nt * 16 + (quad << 2);
    f32x4 sum = *(const f32x4*)(&buf[0][il][o0]);
    sum += *(const f32x4*)(&buf[1][il][o0]);
    sum += *(const f32x4*)(&buf[2][il][o0]);
    sum += *(const f32x4*)(&buf[3][il][o0]);
    float4 v;
    v.x = fmaxf(sum[0] * inv, 0.f);
    v.y = fmaxf(sum[1] * inv, 0.f);
    v.z = fmaxf(sum[2] * inv, 0.f);
    v.w = fmaxf(sum[3] * inv, 0.f);
    *(float4*)(op + o0) = v;
  }
}

extern "C" void kernel_launch(void* const* d_in, const int* in_sizes, int n_in,
                              void* d_out, int out_size, void* d_ws, size_t ws_size,
                              hipStream_t stream) {
  const float* x = (const float*)d_in[0];
  const int* adj = (const int*)d_in[1];
  const float* W = (const float*)d_in[2];
  const float* a = (const float*)d_in[3];
  float* out = (float*)d_out;
  // workspace: whT bf16 [8][128][WPITCH] | s fp32 [16384] | d fp32 [16384]
  unsigned short* whT = (unsigned short*)d_ws;
  float* s = (float*)((char*)d_ws + (size_t)8 * 128 * WPITCH * 2);
  float* dv = s + 16384;
  gat_wh<<<512, 256, 0, stream>>>(x, W, a, whT, s, dv);
  gat_attn<<<1024, 256, 0, stream>>>(adj, whT, s, dv, out);
}

// Round 5
// 300.540 us; speedup vs baseline: 1.1933x; 1.0371x over previous
//
#include <hip/hip_runtime.h>
#include <hip/hip_bf16.h>
#include <stdint.h>

#define GAT_ALPHA 0.2f
#define LOG2E 1.4426950408889634f

typedef __attribute__((ext_vector_type(8))) __bf16 bf16x8;
typedef __attribute__((ext_vector_type(4))) float f32x4;

union B8 {
  bf16x8 b;
  unsigned short u[8];
  int4 i4;
};

__device__ __forceinline__ unsigned short f2bf(float f) {
  unsigned int u = __float_as_uint(f);
  u += 0x7fffu + ((u >> 16) & 1u);   // RNE; inputs are finite
  return (unsigned short)(u >> 16);
}

// async global->LDS DMA, 16B per lane: dest = lds_base + lane*16 (wave-uniform base)
__device__ __forceinline__ void dma16(const void* g, void* l) {
  __builtin_amdgcn_global_load_lds(
      (const __attribute__((address_space(1))) unsigned int*)g,
      (__attribute__((address_space(3))) unsigned int*)l, 16, 0, 0);
}

// ---------------- Kernel P: pack adj int32 -> bitmask (128 MB -> 4 MB) -------------
// Wave reads 256 consecutive ints as 4 coalesced dword loads; 4 ballots; lane0 writes.
__global__ __launch_bounds__(256) void gat_pack(
    const int* __restrict__ adj, unsigned long long* __restrict__ mask) {
  const int tid = threadIdx.x;
  const int lane = tid & 63;
  const int wgl = (blockIdx.x * 256 + tid) >> 6;   // global wave id, 4096 waves
  for (int it = wgl; it < 131072; it += 4096) {    // 33554432 ints / 256 per iter
    const size_t base = (size_t)it << 8;
    const int* p = adj + base + lane;
    int a0 = p[0], a1 = p[64], a2 = p[128], a3 = p[192];
    unsigned long long m0 = __ballot(a0 != 0);
    unsigned long long m1 = __ballot(a1 != 0);
    unsigned long long m2 = __ballot(a2 != 0);
    unsigned long long m3 = __ballot(a3 != 0);
    if (lane == 0) {
      unsigned long long* mp = mask + (base >> 6);
      mp[0] = m0; mp[1] = m1; mp[2] = m2; mp[3] = m3;
    }
  }
}

// ---------------- Kernel A: wh = x @ W^T (fp32), emit whTf (bf16 MFMA-frag order) --
// whTf layout: [b][jc(=j/32)][nt(=o/16)][512 shorts] where within a 16x32 tile,
// lane L holds A[m=L&15][k=(L>>4)*8+u] at shorts [L*8+u]. Also emits s, d (fp32).
__global__ __launch_bounds__(256, 2) void gat_wh(
    const float* __restrict__ x, const float* __restrict__ W,
    const float* __restrict__ a, unsigned short* __restrict__ whTf,
    float* __restrict__ s_out, float* __restrict__ d_out) {
  __shared__ float X[32][260];
  const int tid = threadIdx.x;
  const int row0 = blockIdx.x * 32;
  {
    const int rr = tid >> 3;
    const int seg = (tid & 7) << 2;
    const float* xrow = x + (size_t)(row0 + rr) * 256;
#pragma unroll
    for (int it = 0; it < 8; ++it) {
      const int k = seg + it * 32;
      *(float4*)(&X[rr][k]) = *(const float4*)(xrow + k);
    }
  }
  __syncthreads();
  const int lane32 = tid & 31;
  const int r0 = (tid >> 5) << 2;
  float acc[4][4];
#pragma unroll
  for (int m = 0; m < 4; ++m)
#pragma unroll
    for (int r = 0; r < 4; ++r) acc[m][r] = 0.f;
  const float* W0 = W + (size_t)lane32 * 256;

  float4 xv[2][4], wv[2][4];
#pragma unroll
  for (int r = 0; r < 4; ++r) xv[0][r] = *(const float4*)(&X[r0 + r][0]);
#pragma unroll
  for (int m = 0; m < 4; ++m) wv[0][m] = *(const float4*)(W0 + m * 8192);
#pragma unroll
  for (int k4 = 0; k4 < 64; ++k4) {
    const int cur = k4 & 1, nxt = cur ^ 1;
    if (k4 < 63) {
      const int kn = (k4 + 1) << 2;
#pragma unroll
      for (int r = 0; r < 4; ++r) xv[nxt][r] = *(const float4*)(&X[r0 + r][kn]);
#pragma unroll
      for (int m = 0; m < 4; ++m) wv[nxt][m] = *(const float4*)(W0 + m * 8192 + kn);
    }
#pragma unroll
    for (int m = 0; m < 4; ++m)
#pragma unroll
      for (int r = 0; r < 4; ++r) {
        acc[m][r] = fmaf(wv[cur][m].x, xv[cur][r].x, acc[m][r]);
        acc[m][r] = fmaf(wv[cur][m].y, xv[cur][r].y, acc[m][r]);
        acc[m][r] = fmaf(wv[cur][m].z, xv[cur][r].z, acc[m][r]);
        acc[m][r] = fmaf(wv[cur][m].w, xv[cur][r].w, acc[m][r]);
      }
  }
  float asrc[4], adst[4];
#pragma unroll
  for (int m = 0; m < 4; ++m) {
    asrc[m] = a[lane32 + 32 * m];
    adst[m] = a[128 + lane32 + 32 * m];
  }
  float sp[4], dp[4];
#pragma unroll
  for (int r = 0; r < 4; ++r) {
    sp[r] = acc[0][r] * asrc[0] + acc[1][r] * asrc[1] + acc[2][r] * asrc[2] + acc[3][r] * asrc[3];
    dp[r] = acc[0][r] * adst[0] + acc[1][r] * adst[1] + acc[2][r] * adst[2] + acc[3][r] * adst[3];
  }
#pragma unroll
  for (int off = 16; off >= 1; off >>= 1) {
#pragma unroll
    for (int r = 0; r < 4; ++r) {
      sp[r] += __shfl_xor(sp[r], off, 64);
      dp[r] += __shfl_xor(dp[r], off, 64);
    }
  }
  if (lane32 == 0) {
#pragma unroll
    for (int r = 0; r < 4; ++r) {
      s_out[row0 + r0 + r] = sp[r];
      d_out[row0 + r0 + r] = dp[r];
    }
  }
  // fragment-order write: rows row0+r0+r are k-indices kk=r0+r of tile jc
  const int b = row0 >> 11;
  const int jc = (row0 & 2047) >> 5;   // 32-aligned block => constant per block
  const int q = r0 >> 3;               // k-quad
  const int u0 = r0 & 7;               // 0 or 4: 4 consecutive u slots
#pragma unroll
  for (int m = 0; m < 4; ++m) {
    const int o = lane32 + 32 * m;
    const int nt = o >> 4, m16 = o & 15;
    uint2 pk;
    pk.x = (unsigned int)f2bf(acc[m][0]) | ((unsigned int)f2bf(acc[m][1]) << 16);
    pk.y = (unsigned int)f2bf(acc[m][2]) | ((unsigned int)f2bf(acc[m][3]) << 16);
    const size_t addr = ((((size_t)b * 64 + jc) * 8 + nt) << 9) + ((m16 + 16 * q) << 3) + u0;
    *(uint2*)(whTf + addr) = pk;
  }
}

// ---------------- Kernel B: masked attention, LDS-DMA pipelined MFMA ---------------
// 256 blocks (8 b x 32 tiles), 256 thr = 4 waves x 16 rows. All waves share each
// 8 KB V-chunk (j-width 32, all 128 o) double-buffered in LDS via global_load_lds.
// Bitmask (16 rows x 2048 bits) and d staged in LDS. No max-sub softmax (e <= ~18).
__global__ __launch_bounds__(256) void gat_attn(
    const unsigned int* __restrict__ mask32, const unsigned short* __restrict__ whTf,
    const float* __restrict__ s, const float* __restrict__ dvec,
    float* __restrict__ out) {
  __shared__ unsigned short vbuf[2][8][512];   // 16 KB: [buf][nt][frag shorts]
  __shared__ unsigned int maskl[64][68];       // 17 KB: row-padded (+4) bitmask words
  __shared__ float dl[2048];                   // 8 KB
  const int tid = threadIdx.x;
  const int wave = tid >> 6;
  const int lane = tid & 63;
  const int il = lane & 15;
  const int quad = lane >> 4;
  const int qo = quad << 3;
  const int b = blockIdx.x >> 5;
  const int tile = blockIdx.x & 31;
  const int rbase = tile * 64;                 // block's first row within batch
  // ---- stage d (8 KB) ----
  {
    const float* dsrc = dvec + ((size_t)b << 11);
#pragma unroll
    for (int it = 0; it < 2; ++it) {
      const int idx = it * 1024 + tid * 4;
      *(float4*)(&dl[idx]) = *(const float4*)(dsrc + idx);
    }
  }
  // ---- stage bitmask: 64 rows x 64 words, contiguous 16 KB in global ----
  {
    const unsigned int* msrc = mask32 + (((size_t)b << 11) + rbase) * 64;
    const int c4 = (tid & 15) << 2;
#pragma unroll
    for (int kk = 0; kk < 4; ++kk) {
      const int r = (tid >> 4) + kk * 16;
      *(int4*)(&maskl[r][c4]) = *(const int4*)(msrc + r * 64 + c4);
    }
  }
  // ---- prologue DMA: chunk 0 into vbuf[0]; each wave covers nt = 2w, 2w+1 ----
  const unsigned short* whTb = whTf + (((size_t)b * 64) << 12);  // b*64*8*512
  {
#pragma unroll
    for (int h = 0; h < 2; ++h) {
      const int nt = wave * 2 + h;
      dma16(whTb + ((size_t)nt << 9) + (lane << 3), &vbuf[0][nt][0]);
    }
  }
  const int i = rbase + wave * 16 + il;
  const size_t browi = ((size_t)b << 11) + i;
  const float sv = s[browi];
  const int mrow = wave * 16 + il;

  f32x4 acc[8];
#pragma unroll
  for (int nt = 0; nt < 8; ++nt) acc[nt] = (f32x4){0.f, 0.f, 0.f, 0.f};
  float den = 0.f;
  __syncthreads();   // drains prologue DMA (vmcnt) + LDS stores

#pragma unroll 4
  for (int t = 0; t < 64; ++t) {
    const int cur = t & 1, nxt = cur ^ 1;
    if (t < 63) {    // DMA next chunk while computing on current
#pragma unroll
      for (int h = 0; h < 2; ++h) {
        const int nt = wave * 2 + h;
        dma16(whTb + (((size_t)(t + 1) * 8 + nt) << 9) + (lane << 3), &vbuf[nxt][nt][0]);
      }
    }
    const int j0 = t * 32;
    const unsigned int mword = maskl[mrow][t];
    const float4 d0 = *(const float4*)(&dl[j0 + qo]);
    const float4 d1 = *(const float4*)(&dl[j0 + qo + 4]);
    const float dd[8] = {d0.x, d0.y, d0.z, d0.w, d1.x, d1.y, d1.z, d1.w};
    B8 af[8];
#pragma unroll
    for (int nt = 0; nt < 8; ++nt)
      af[nt].i4 = *(const int4*)((const char*)&vbuf[cur][nt][0] + lane * 16);
    B8 pf;
#pragma unroll
    for (int u = 0; u < 8; ++u) {
      float e = sv + dd[u];
      e = fmaxf(e, GAT_ALPHA * e);                 // leaky relu
      float p = __builtin_amdgcn_exp2f(e * LOG2E); // no max-sub: e <= ~18
      p = ((mword >> (qo + u)) & 1u) ? p : 0.f;
      den += p;
      pf.u[u] = f2bf(p);
    }
#pragma unroll
    for (int nt = 0; nt < 8; ++nt)
      acc[nt] = __builtin_amdgcn_mfma_f32_16x16x32_bf16(af[nt].b, pf.b, acc[nt], 0, 0, 0);
    __syncthreads();  // own DMA drained (vmcnt0) + all waves done with vbuf[cur]
  }
  // den: sum the 4 quad-partials for row il
  den += __shfl_xor(den, 16, 64);
  den += __shfl_xor(den, 32, 64);
  const float inv = 1.0f / den;
  // D layout: col=il=i, row=quad*4+reg = o within nt tile -> 8 coalesced float4
  float* op = out + browi * 128;
#pragma unroll
  for (int nt = 0; nt < 8; ++nt) {
    float4 v;
    v.x = fmaxf(acc[nt][0] * inv, 0.f);
    v.y = fmaxf(acc[nt][1] * inv, 0.f);
    v.z = fmaxf(acc[nt][2] * inv, 0.f);
    v.w = fmaxf(acc[nt][3] * inv, 0.f);
    *(float4*)(op + nt * 16 + quad * 4) = v;
  }
}

extern "C" void kernel_launch(void* const* d_in, const int* in_sizes, int n_in,
                              void* d_out, int out_size, void* d_ws, size_t ws_size,
                              hipStream_t stream) {
  const float* x = (const float*)d_in[0];
  const int* adj = (const int*)d_in[1];
  const float* W = (const float*)d_in[2];
  const float* a = (const float*)d_in[3];
  float* out = (float*)d_out;
  // ws: whTf bf16 4 MB | mask 4 MB | s fp32 64 KB | d fp32 64 KB  (8.52 MB total)
  unsigned short* whTf = (unsigned short*)d_ws;
  unsigned long long* mask = (unsigned long long*)((char*)d_ws + (size_t)4 * 1024 * 1024);
  float* s = (float*)((char*)d_ws + (size_t)8 * 1024 * 1024);
  float* dv = s + 16384;
  gat_pack<<<1024, 256, 0, stream>>>(adj, mask);
  gat_wh<<<512, 256, 0, stream>>>(x, W, a, whTf, s, dv);
  gat_attn<<<256, 256, 0, stream>>>((const unsigned int*)mask, whTf, s, dv, out);
}

// Round 6
// 268.063 us; speedup vs baseline: 1.3378x; 1.1212x over previous
//
#include <hip/hip_runtime.h>
#include <hip/hip_bf16.h>
#include <stdint.h>

#define GAT_ALPHA 0.2f
#define LOG2E 1.4426950408889634f

typedef __attribute__((ext_vector_type(8))) __bf16 bf16x8;
typedef __attribute__((ext_vector_type(4))) float f32x4;

union B8 {
  bf16x8 b;
  unsigned short u[8];
  int4 i4;
};

__device__ __forceinline__ unsigned short f2bf(float f) {
  unsigned int u = __float_as_uint(f);
  u += 0x7fffu + ((u >> 16) & 1u);   // RNE; inputs are finite
  return (unsigned short)(u >> 16);
}

// async global->LDS DMA, 16B per lane: dest = lds_base + lane*16 (wave-uniform base)
__device__ __forceinline__ void dma16(const void* g, void* l) {
  __builtin_amdgcn_global_load_lds(
      (const __attribute__((address_space(1))) unsigned int*)g,
      (__attribute__((address_space(3))) unsigned int*)l, 16, 0, 0);
}

// ---------------- Kernel P: pack adj int32 -> bitmask (128 MB -> 4 MB) -------------
__global__ __launch_bounds__(256) void gat_pack(
    const int* __restrict__ adj, unsigned long long* __restrict__ mask) {
  const int tid = threadIdx.x;
  const int lane = tid & 63;
  const int wgl = (blockIdx.x * 256 + tid) >> 6;   // global wave id, 4096 waves
  for (int it = wgl; it < 131072; it += 4096) {
    const size_t base = (size_t)it << 8;
    const int* p = adj + base + lane;
    int a0 = p[0], a1 = p[64], a2 = p[128], a3 = p[192];
    unsigned long long m0 = __ballot(a0 != 0);
    unsigned long long m1 = __ballot(a1 != 0);
    unsigned long long m2 = __ballot(a2 != 0);
    unsigned long long m3 = __ballot(a3 != 0);
    if (lane == 0) {
      unsigned long long* mp = mask + (base >> 6);
      mp[0] = m0; mp[1] = m1; mp[2] = m2; mp[3] = m3;
    }
  }
}

// ---------------- Kernel A: wh = x @ W^T (fp32), emit whTf (bf16 MFMA-frag order) --
// v2: W staged in LDS by k-chunks (128x64 fp32, coalesced cooperative load) so the
// compute loop never issues 64-segment gathers (R5 bottleneck: TA request rate).
// whTf layout: [b][jc(=j/32)][nt(=o/16)][512 shorts]; lane L holds A[m=L&15][k=(L>>4)*8+u].
__global__ __launch_bounds__(256, 2) void gat_wh(
    const float* __restrict__ x, const float* __restrict__ W,
    const float* __restrict__ a, unsigned short* __restrict__ whTf,
    float* __restrict__ s_out, float* __restrict__ d_out) {
  __shared__ float X[32][260];    // 33.3 KB
  __shared__ float Wt[128][68];   // 34.8 KB  (pitch 68: 2-way conflicts only = free)
  const int tid = threadIdx.x;
  const int row0 = blockIdx.x * 32;
  {
    const int rr = tid >> 3;
    const int seg = (tid & 7) << 2;
    const float* xrow = x + (size_t)(row0 + rr) * 256;
#pragma unroll
    for (int it = 0; it < 8; ++it) {
      const int k = seg + it * 32;
      *(float4*)(&X[rr][k]) = *(const float4*)(xrow + k);
    }
  }
  const int lane32 = tid & 31;
  const int r0 = (tid >> 5) << 2;
  float acc[4][4];
#pragma unroll
  for (int m = 0; m < 4; ++m)
#pragma unroll
    for (int r = 0; r < 4; ++r) acc[m][r] = 0.f;

  for (int kc = 0; kc < 4; ++kc) {
    __syncthreads();               // X ready (kc=0) / Wt no longer in use (kc>0)
    // stage Wt chunk: 128 rows x 64 floats, 16B/thread/pass, 4 segments per wave-inst
#pragma unroll
    for (int p = 0; p < 8; ++p) {
      const int f = p * 1024 + tid * 4;
      const int row = f >> 6, col = f & 63;
      *(float4*)(&Wt[row][col]) = *(const float4*)(W + row * 256 + kc * 64 + col);
    }
    __syncthreads();
    const int kb = kc << 6;
#pragma unroll
    for (int k4 = 0; k4 < 16; ++k4) {
      const int kk = k4 << 2;
      float4 xv[4], wv[4];
#pragma unroll
      for (int r = 0; r < 4; ++r) xv[r] = *(const float4*)(&X[r0 + r][kb + kk]);
#pragma unroll
      for (int m = 0; m < 4; ++m) wv[m] = *(const float4*)(&Wt[lane32 + 32 * m][kk]);
#pragma unroll
      for (int m = 0; m < 4; ++m)
#pragma unroll
        for (int r = 0; r < 4; ++r) {
          acc[m][r] = fmaf(wv[m].x, xv[r].x, acc[m][r]);
          acc[m][r] = fmaf(wv[m].y, xv[r].y, acc[m][r]);
          acc[m][r] = fmaf(wv[m].z, xv[r].z, acc[m][r]);
          acc[m][r] = fmaf(wv[m].w, xv[r].w, acc[m][r]);
        }
    }
  }
  float asrc[4], adst[4];
#pragma unroll
  for (int m = 0; m < 4; ++m) {
    asrc[m] = a[lane32 + 32 * m];
    adst[m] = a[128 + lane32 + 32 * m];
  }
  float sp[4], dp[4];
#pragma unroll
  for (int r = 0; r < 4; ++r) {
    sp[r] = acc[0][r] * asrc[0] + acc[1][r] * asrc[1] + acc[2][r] * asrc[2] + acc[3][r] * asrc[3];
    dp[r] = acc[0][r] * adst[0] + acc[1][r] * adst[1] + acc[2][r] * adst[2] + acc[3][r] * adst[3];
  }
#pragma unroll
  for (int off = 16; off >= 1; off >>= 1) {
#pragma unroll
    for (int r = 0; r < 4; ++r) {
      sp[r] += __shfl_xor(sp[r], off, 64);
      dp[r] += __shfl_xor(dp[r], off, 64);
    }
  }
  if (lane32 == 0) {
#pragma unroll
    for (int r = 0; r < 4; ++r) {
      s_out[row0 + r0 + r] = sp[r];
      d_out[row0 + r0 + r] = dp[r];
    }
  }
  // fragment-order write (unchanged layout; attn reads this exact order)
  const int b = row0 >> 11;
  const int jc = (row0 & 2047) >> 5;
  const int q = r0 >> 3;
  const int u0 = r0 & 7;
#pragma unroll
  for (int m = 0; m < 4; ++m) {
    const int o = lane32 + 32 * m;
    const int nt = o >> 4, m16 = o & 15;
    uint2 pk;
    pk.x = (unsigned int)f2bf(acc[m][0]) | ((unsigned int)f2bf(acc[m][1]) << 16);
    pk.y = (unsigned int)f2bf(acc[m][2]) | ((unsigned int)f2bf(acc[m][3]) << 16);
    const size_t addr = ((((size_t)b * 64 + jc) * 8 + nt) << 9) + ((m16 + 16 * q) << 3) + u0;
    *(uint2*)(whTf + addr) = pk;
  }
}

// ---------------- Kernel B: masked attention, LDS-DMA pipelined MFMA ---------------
// 256 blocks; b = blk&7 so all 32 tiles of a batch land on one XCD -> whTf (0.5 MB)
// + mask (0.5 MB) are L2-resident per XCD. 2 chunks per barrier halves drain count.
__global__ __launch_bounds__(256) void gat_attn(
    const unsigned int* __restrict__ mask32, const unsigned short* __restrict__ whTf,
    const float* __restrict__ s, const float* __restrict__ dvec,
    float* __restrict__ out) {
  __shared__ unsigned short vbuf[2][2][8][512];  // 32 KB: [buf][chunk][nt][frag]
  __shared__ unsigned int maskl[64][68];         // 17.4 KB
  __shared__ float dl[2048];                     // 8 KB
  const int tid = threadIdx.x;
  const int wave = tid >> 6;
  const int lane = tid & 63;
  const int il = lane & 15;
  const int quad = lane >> 4;
  const int qo = quad << 3;
  const int b = blockIdx.x & 7;        // XCD swizzle: batch pinned to one XCD
  const int tile = blockIdx.x >> 3;
  const int rbase = tile * 64;
  {
    const float* dsrc = dvec + ((size_t)b << 11);
#pragma unroll
    for (int it = 0; it < 2; ++it) {
      const int idx = it * 1024 + tid * 4;
      *(float4*)(&dl[idx]) = *(const float4*)(dsrc + idx);
    }
  }
  {
    const unsigned int* msrc = mask32 + (((size_t)b << 11) + rbase) * 64;
    const int c4 = (tid & 15) << 2;
#pragma unroll
    for (int kk = 0; kk < 4; ++kk) {
      const int r = (tid >> 4) + kk * 16;
      *(int4*)(&maskl[r][c4]) = *(const int4*)(msrc + r * 64 + c4);
    }
  }
  const unsigned short* whTb = whTf + (((size_t)b * 64) << 12);
  {
#pragma unroll
    for (int h = 0; h < 2; ++h) {
      const int nt = wave * 2 + h;
      dma16(whTb + ((size_t)(0 * 8 + nt) << 9) + (lane << 3), &vbuf[0][0][nt][0]);
      dma16(whTb + ((size_t)(1 * 8 + nt) << 9) + (lane << 3), &vbuf[0][1][nt][0]);
    }
  }
  const int i = rbase + wave * 16 + il;
  const size_t browi = ((size_t)b << 11) + i;
  const float sv = s[browi];
  const int mrow = wave * 16 + il;

  f32x4 acc[8];
#pragma unroll
  for (int nt = 0; nt < 8; ++nt) acc[nt] = (f32x4){0.f, 0.f, 0.f, 0.f};
  float den = 0.f;
  __syncthreads();   // drains prologue DMA + LDS stores

#pragma unroll 2
  for (int T = 0; T < 32; ++T) {
    const int cur = T & 1, nxt = cur ^ 1;
    if (T < 31) {    // DMA next chunk-pair while computing on current pair
#pragma unroll
      for (int h = 0; h < 2; ++h) {
        const int nt = wave * 2 + h;
        dma16(whTb + (((size_t)(2 * T + 2) * 8 + nt) << 9) + (lane << 3), &vbuf[nxt][0][nt][0]);
        dma16(whTb + (((size_t)(2 * T + 3) * 8 + nt) << 9) + (lane << 3), &vbuf[nxt][1][nt][0]);
      }
    }
#pragma unroll
    for (int c = 0; c < 2; ++c) {
      const int tt = 2 * T + c;
      const int j0 = tt * 32;
      const unsigned int mword = maskl[mrow][tt];
      const float4 d0 = *(const float4*)(&dl[j0 + qo]);
      const float4 d1 = *(const float4*)(&dl[j0 + qo + 4]);
      const float dd[8] = {d0.x, d0.y, d0.z, d0.w, d1.x, d1.y, d1.z, d1.w};
      B8 af[8];
#pragma unroll
      for (int nt = 0; nt < 8; ++nt)
        af[nt].i4 = *(const int4*)((const char*)&vbuf[cur][c][nt][0] + lane * 16);
      B8 pf;
#pragma unroll
      for (int u = 0; u < 8; ++u) {
        float e = sv + dd[u];
        e = fmaxf(e, GAT_ALPHA * e);                 // leaky relu
        float p = __builtin_amdgcn_exp2f(e * LOG2E); // no max-sub: e <= ~18
        p = ((mword >> (qo + u)) & 1u) ? p : 0.f;
        den += p;
        pf.u[u] = f2bf(p);
      }
#pragma unroll
      for (int nt = 0; nt < 8; ++nt)
        acc[nt] = __builtin_amdgcn_mfma_f32_16x16x32_bf16(af[nt].b, pf.b, acc[nt], 0, 0, 0);
    }
    __syncthreads();  // all waves done with vbuf[cur]; own next-DMA drained
  }
  den += __shfl_xor(den, 16, 64);
  den += __shfl_xor(den, 32, 64);
  const float inv = 1.0f / den;
  float* op = out + browi * 128;
#pragma unroll
  for (int nt = 0; nt < 8; ++nt) {
    float4 v;
    v.x = fmaxf(acc[nt][0] * inv, 0.f);
    v.y = fmaxf(acc[nt][1] * inv, 0.f);
    v.z = fmaxf(acc[nt][2] * inv, 0.f);
    v.w = fmaxf(acc[nt][3] * inv, 0.f);
    *(float4*)(op + nt * 16 + quad * 4) = v;
  }
}

extern "C" void kernel_launch(void* const* d_in, const int* in_sizes, int n_in,
                              void* d_out, int out_size, void* d_ws, size_t ws_size,
                              hipStream_t stream) {
  const float* x = (const float*)d_in[0];
  const int* adj = (const int*)d_in[1];
  const float* W = (const float*)d_in[2];
  const float* a = (const float*)d_in[3];
  float* out = (float*)d_out;
  // ws: whTf bf16 4 MB | mask 4 MB | s fp32 64 KB | d fp32 64 KB
  unsigned short* whTf = (unsigned short*)d_ws;
  unsigned long long* mask = (unsigned long long*)((char*)d_ws + (size_t)4 * 1024 * 1024);
  float* s = (float*)((char*)d_ws + (size_t)8 * 1024 * 1024);
  float* dv = s + 16384;
  gat_pack<<<1024, 256, 0, stream>>>(adj, mask);
  gat_wh<<<512, 256, 0, stream>>>(x, W, a, whTf, s, dv);
  gat_attn<<<256, 256, 0, stream>>>((const unsigned int*)mask, whTf, s, dv, out);
}

// Round 7
// 255.534 us; speedup vs baseline: 1.4034x; 1.0490x over previous
//
#include <hip/hip_runtime.h>
#include <hip/hip_bf16.h>
#include <stdint.h>

#define GAT_ALPHA 0.2f
#define LOG2E 1.4426950408889634f

typedef __attribute__((ext_vector_type(8))) __bf16 bf16x8;
typedef __attribute__((ext_vector_type(4))) float f32x4;

union B8 {
  bf16x8 b;
  unsigned short u[8];
  unsigned int w[4];
  int4 i4;
};

// packed fp32x2 -> bf16x2 RNE (v_cvt_pk_bf16_f32 on gfx950)
__device__ __forceinline__ unsigned int pk2bf(float lo, float hi) {
  union { __hip_bfloat162 h; unsigned int u; } cv;
  cv.h = __float22bfloat162_rn(make_float2(lo, hi));
  return cv.u;
}

// ---------------- Kernel P: pack adj int32 -> bitmask (128 MB -> 4 MB) -------------
__global__ __launch_bounds__(256) void gat_pack(
    const int* __restrict__ adj, unsigned long long* __restrict__ mask) {
  const int tid = threadIdx.x;
  const int lane = tid & 63;
  const int wgl = (blockIdx.x * 256 + tid) >> 6;   // global wave id, 4096 waves
  for (int it = wgl; it < 131072; it += 4096) {
    const size_t base = (size_t)it << 8;
    const int* p = adj + base + lane;
    int a0 = p[0], a1 = p[64], a2 = p[128], a3 = p[192];
    unsigned long long m0 = __ballot(a0 != 0);
    unsigned long long m1 = __ballot(a1 != 0);
    unsigned long long m2 = __ballot(a2 != 0);
    unsigned long long m3 = __ballot(a3 != 0);
    if (lane == 0) {
      unsigned long long* mp = mask + (base >> 6);
      mp[0] = m0; mp[1] = m1; mp[2] = m2; mp[3] = m3;
    }
  }
}

// ---------------- Kernel A: wh = x @ W^T via bf16 MFMA (fp32 accumulate) -----------
// 256 blocks x 256 thr (4 waves); block = 64 rows x 128 o. Wave w: rows 16w..16w+15.
// A-frags (x) loaded from global fp32 + cvt_pk (each byte read once, 16 loads in
// flight per wave). W staged in LDS as bf16 frags, two 32 KB k-halves (<=64KB LDS).
// s,d computed from fp32 accumulators; whTf written in attn's frag order.
__global__ __launch_bounds__(256, 2) void gat_wh(
    const float* __restrict__ x, const float* __restrict__ W,
    const float* __restrict__ a, unsigned short* __restrict__ whTf,
    float* __restrict__ s_out, float* __restrict__ d_out) {
  __shared__ unsigned short WF[8][4][512];   // 32 KB: [nt][kc_local][frag shorts]
  const int tid = threadIdx.x;
  const int wave = tid >> 6, lane = tid & 63;
  const int il = lane & 15, quad = lane >> 4;
  const int row0 = blockIdx.x * 64;
  const int i = row0 + wave * 16 + il;
  // ---- all 16 A-frag x loads issued up front; convert to bf16 frags ----
  B8 av[8];
  {
    const float* xp = x + (size_t)i * 256 + quad * 8;
#pragma unroll
    for (int kc = 0; kc < 8; ++kc) {
      float4 lo = *(const float4*)(xp + kc * 32);
      float4 hi = *(const float4*)(xp + kc * 32 + 4);
      av[kc].w[0] = pk2bf(lo.x, lo.y);
      av[kc].w[1] = pk2bf(lo.z, lo.w);
      av[kc].w[2] = pk2bf(hi.x, hi.y);
      av[kc].w[3] = pk2bf(hi.z, hi.w);
    }
  }
  f32x4 acc[8];
#pragma unroll
  for (int nt = 0; nt < 8; ++nt) acc[nt] = (f32x4){0.f, 0.f, 0.f, 0.f};
#pragma unroll
  for (int h = 0; h < 2; ++h) {
    if (h) __syncthreads();              // kc 0..3 consumers done before restage
    // stage W half h: 128 rows x 128 cols fp32, coalesced, frag-order bf16 in LDS
#pragma unroll
    for (int p = 0; p < 16; ++p) {
      const int f = p * 1024 + tid * 4;
      const int o = f >> 7, kk = f & 127;
      float4 v = *(const float4*)(W + o * 256 + h * 128 + kk);
      uint2 pk;
      pk.x = pk2bf(v.x, v.y);
      pk.y = pk2bf(v.z, v.w);
      *(uint2*)(&WF[o >> 4][kk >> 5][((o & 15) + (((kk & 31) >> 3) << 4)) * 8 + (kk & 7)]) = pk;
    }
    __syncthreads();
#pragma unroll
    for (int kl = 0; kl < 4; ++kl) {
      const int kc = h * 4 + kl;
#pragma unroll
      for (int nt = 0; nt < 8; ++nt) {
        B8 bv;
        bv.i4 = *(const int4*)(&WF[nt][kl][lane * 8]);
        acc[nt] = __builtin_amdgcn_mfma_f32_16x16x32_bf16(av[kc].b, bv.b, acc[nt], 0, 0, 0);
      }
    }
  }
  // ---- s, d from fp32 accumulators: lane has o = nt*16+il, rows m = quad*4+reg ----
  float asrc[8], adst[8];
#pragma unroll
  for (int nt = 0; nt < 8; ++nt) {
    asrc[nt] = a[nt * 16 + il];
    adst[nt] = a[128 + nt * 16 + il];
  }
  float sp[4], dp[4];
#pragma unroll
  for (int r = 0; r < 4; ++r) {
    float sv = 0.f, dv = 0.f;
#pragma unroll
    for (int nt = 0; nt < 8; ++nt) {
      sv += acc[nt][r] * asrc[nt];
      dv += acc[nt][r] * adst[nt];
    }
    sp[r] = sv; dp[r] = dv;
  }
#pragma unroll
  for (int off = 1; off <= 8; off <<= 1) {
#pragma unroll
    for (int r = 0; r < 4; ++r) {
      sp[r] += __shfl_xor(sp[r], off, 64);   // reduce over il within quad group
      dp[r] += __shfl_xor(dp[r], off, 64);
    }
  }
  if (il == 0) {
#pragma unroll
    for (int r = 0; r < 4; ++r) {
      s_out[row0 + wave * 16 + quad * 4 + r] = sp[r];
      d_out[row0 + wave * 16 + quad * 4 + r] = dp[r];
    }
  }
  // ---- whTf frag-order write (identical layout to R6; attn reads unchanged) ----
  const int b = row0 >> 11;
  const int jc = ((row0 & 2047) >> 5) + (wave >> 1);
  const int kin = ((wave & 1) << 4) + (quad << 2);   // k-in-chunk base of the 4 regs
  const int kq = kin >> 3, u0 = kin & 7;
#pragma unroll
  for (int nt = 0; nt < 8; ++nt) {
    uint2 pk;
    pk.x = pk2bf(acc[nt][0], acc[nt][1]);
    pk.y = pk2bf(acc[nt][2], acc[nt][3]);
    *(uint2*)(whTf + ((((size_t)(b * 64 + jc)) * 8 + nt) << 9) + ((il + (kq << 4)) << 3) + u0) = pk;
  }
}

// async global->LDS DMA, 16B per lane: dest = lds_base + lane*16 (wave-uniform base)
__device__ __forceinline__ void dma16(const void* g, void* l) {
  __builtin_amdgcn_global_load_lds(
      (const __attribute__((address_space(1))) unsigned int*)g,
      (__attribute__((address_space(3))) unsigned int*)l, 16, 0, 0);
}

// ---------------- Kernel B: masked attention, LDS-DMA pipelined MFMA ---------------
// 256 blocks; b = blk&7 pins each batch to one XCD (whTf+mask L2-resident).
// dl holds d*LOG2E, svL = s*LOG2E: lrelu+exp2 with no per-p LOG2E multiply.
__global__ __launch_bounds__(256) void gat_attn(
    const unsigned int* __restrict__ mask32, const unsigned short* __restrict__ whTf,
    const float* __restrict__ s, const float* __restrict__ dvec,
    float* __restrict__ out) {
  __shared__ unsigned short vbuf[2][2][8][512];  // 32 KB: [buf][chunk][nt][frag]
  __shared__ unsigned int maskl[64][68];         // 17.4 KB
  __shared__ float dl[2048];                     // 8 KB (pre-scaled by LOG2E)
  const int tid = threadIdx.x;
  const int wave = tid >> 6;
  const int lane = tid & 63;
  const int il = lane & 15;
  const int quad = lane >> 4;
  const int qo = quad << 3;
  const int b = blockIdx.x & 7;
  const int tile = blockIdx.x >> 3;
  const int rbase = tile * 64;
  {
    const float* dsrc = dvec + ((size_t)b << 11);
#pragma unroll
    for (int it = 0; it < 2; ++it) {
      const int idx = it * 1024 + tid * 4;
      float4 v = *(const float4*)(dsrc + idx);
      v.x *= LOG2E; v.y *= LOG2E; v.z *= LOG2E; v.w *= LOG2E;
      *(float4*)(&dl[idx]) = v;
    }
  }
  {
    const unsigned int* msrc = mask32 + (((size_t)b << 11) + rbase) * 64;
    const int c4 = (tid & 15) << 2;
#pragma unroll
    for (int kk = 0; kk < 4; ++kk) {
      const int r = (tid >> 4) + kk * 16;
      *(int4*)(&maskl[r][c4]) = *(const int4*)(msrc + r * 64 + c4);
    }
  }
  const unsigned short* whTb = whTf + (((size_t)b * 64) << 12);
  {
#pragma unroll
    for (int h = 0; h < 2; ++h) {
      const int nt = wave * 2 + h;
      dma16(whTb + ((size_t)(0 * 8 + nt) << 9) + (lane << 3), &vbuf[0][0][nt][0]);
      dma16(whTb + ((size_t)(1 * 8 + nt) << 9) + (lane << 3), &vbuf[0][1][nt][0]);
    }
  }
  const int i = rbase + wave * 16 + il;
  const size_t browi = ((size_t)b << 11) + i;
  const float svL = s[browi] * LOG2E;
  const int mrow = wave * 16 + il;

  f32x4 acc[8];
#pragma unroll
  for (int nt = 0; nt < 8; ++nt) acc[nt] = (f32x4){0.f, 0.f, 0.f, 0.f};
  float den = 0.f;
  __syncthreads();   // drains prologue DMA + LDS stores

#pragma unroll 2
  for (int T = 0; T < 32; ++T) {
    const int cur = T & 1, nxt = cur ^ 1;
    if (T < 31) {
#pragma unroll
      for (int h = 0; h < 2; ++h) {
        const int nt = wave * 2 + h;
        dma16(whTb + (((size_t)(2 * T + 2) * 8 + nt) << 9) + (lane << 3), &vbuf[nxt][0][nt][0]);
        dma16(whTb + (((size_t)(2 * T + 3) * 8 + nt) << 9) + (lane << 3), &vbuf[nxt][1][nt][0]);
      }
    }
#pragma unroll
    for (int c = 0; c < 2; ++c) {
      const int tt = 2 * T + c;
      const int j0 = tt * 32;
      const unsigned int mword = maskl[mrow][tt];
      const float4 d0 = *(const float4*)(&dl[j0 + qo]);
      const float4 d1 = *(const float4*)(&dl[j0 + qo + 4]);
      const float dd[8] = {d0.x, d0.y, d0.z, d0.w, d1.x, d1.y, d1.z, d1.w};
      B8 af[8];
#pragma unroll
      for (int nt = 0; nt < 8; ++nt)
        af[nt].i4 = *(const int4*)((const char*)&vbuf[cur][c][nt][0] + lane * 16);
      float pv[8];
#pragma unroll
      for (int u = 0; u < 8; ++u) {
        float t0 = svL + dd[u];                       // e * LOG2E
        float e2 = fmaxf(t0, GAT_ALPHA * t0);         // leaky relu (scale-invariant)
        float p = __builtin_amdgcn_exp2f(e2);         // no max-sub: e <= ~18
        p = ((mword >> (qo + u)) & 1u) ? p : 0.f;
        den += p;
        pv[u] = p;
      }
      B8 pf;
      pf.w[0] = pk2bf(pv[0], pv[1]);
      pf.w[1] = pk2bf(pv[2], pv[3]);
      pf.w[2] = pk2bf(pv[4], pv[5]);
      pf.w[3] = pk2bf(pv[6], pv[7]);
#pragma unroll
      for (int nt = 0; nt < 8; ++nt)
        acc[nt] = __builtin_amdgcn_mfma_f32_16x16x32_bf16(af[nt].b, pf.b, acc[nt], 0, 0, 0);
    }
    __syncthreads();  // all waves done with vbuf[cur]; own next-DMA drained
  }
  den += __shfl_xor(den, 16, 64);
  den += __shfl_xor(den, 32, 64);
  const float inv = 1.0f / den;
  float* op = out + browi * 128;
#pragma unroll
  for (int nt = 0; nt < 8; ++nt) {
    float4 v;
    v.x = fmaxf(acc[nt][0] * inv, 0.f);
    v.y = fmaxf(acc[nt][1] * inv, 0.f);
    v.z = fmaxf(acc[nt][2] * inv, 0.f);
    v.w = fmaxf(acc[nt][3] * inv, 0.f);
    *(float4*)(op + nt * 16 + quad * 4) = v;
  }
}

extern "C" void kernel_launch(void* const* d_in, const int* in_sizes, int n_in,
                              void* d_out, int out_size, void* d_ws, size_t ws_size,
                              hipStream_t stream) {
  const float* x = (const float*)d_in[0];
  const int* adj = (const int*)d_in[1];
  const float* W = (const float*)d_in[2];
  const float* a = (const float*)d_in[3];
  float* out = (float*)d_out;
  // ws: whTf bf16 4 MB | mask 4 MB | s fp32 64 KB | d fp32 64 KB
  unsigned short* whTf = (unsigned short*)d_ws;
  unsigned long long* mask = (unsigned long long*)((char*)d_ws + (size_t)4 * 1024 * 1024);
  float* s = (float*)((char*)d_ws + (size_t)8 * 1024 * 1024);
  float* dv = s + 16384;
  gat_pack<<<1024, 256, 0, stream>>>(adj, mask);
  gat_wh<<<256, 256, 0, stream>>>(x, W, a, whTf, s, dv);
  gat_attn<<<256, 256, 0, stream>>>((const unsigned int*)mask, whTf, s, dv, out);
}

// Round 8
// 236.260 us; speedup vs baseline: 1.5179x; 1.0816x over previous
//
#include <hip/hip_runtime.h>
#include <hip/hip_bf16.h>
#include <stdint.h>

#define GAT_ALPHA 0.2f
#define LOG2E 1.4426950408889634f

typedef __attribute__((ext_vector_type(8))) __bf16 bf16x8;
typedef __attribute__((ext_vector_type(4))) float f32x4;

union B8 {
  bf16x8 b;
  unsigned short u[8];
  unsigned int w[4];
  int4 i4;
};

// packed fp32x2 -> bf16x2 RNE (v_cvt_pk_bf16_f32 on gfx950)
__device__ __forceinline__ unsigned int pk2bf(float lo, float hi) {
  union { __hip_bfloat162 h; unsigned int u; } cv;
  cv.h = __float22bfloat162_rn(make_float2(lo, hi));
  return cv.u;
}

// async global->LDS DMA, 16B per lane: dest = lds_base + lane*16 (wave-uniform base)
__device__ __forceinline__ void dma16(const void* g, void* l) {
  __builtin_amdgcn_global_load_lds(
      (const __attribute__((address_space(1))) unsigned int*)g,
      (__attribute__((address_space(3))) unsigned int*)l, 16, 0, 0);
}

// ---------------- Kernel A: wh = x @ W^T via bf16 MFMA (fp32 accumulate) -----------
// 256 blocks x 256 thr (4 waves); block = 64 rows x 128 o. Wave w: rows 16w..16w+15.
// A-frags (x) loaded from global fp32 + cvt_pk (each byte read once). W staged in LDS
// as bf16 frags, two 32 KB k-halves. s,d from fp32 accumulators; whTf in frag order.
__global__ __launch_bounds__(256, 2) void gat_wh(
    const float* __restrict__ x, const float* __restrict__ W,
    const float* __restrict__ a, unsigned short* __restrict__ whTf,
    float* __restrict__ s_out, float* __restrict__ d_out) {
  __shared__ unsigned short WF[8][4][512];   // 32 KB: [nt][kc_local][frag shorts]
  const int tid = threadIdx.x;
  const int wave = tid >> 6, lane = tid & 63;
  const int il = lane & 15, quad = lane >> 4;
  const int row0 = blockIdx.x * 64;
  const int i = row0 + wave * 16 + il;
  B8 av[8];
  {
    const float* xp = x + (size_t)i * 256 + quad * 8;
#pragma unroll
    for (int kc = 0; kc < 8; ++kc) {
      float4 lo = *(const float4*)(xp + kc * 32);
      float4 hi = *(const float4*)(xp + kc * 32 + 4);
      av[kc].w[0] = pk2bf(lo.x, lo.y);
      av[kc].w[1] = pk2bf(lo.z, lo.w);
      av[kc].w[2] = pk2bf(hi.x, hi.y);
      av[kc].w[3] = pk2bf(hi.z, hi.w);
    }
  }
  f32x4 acc[8];
#pragma unroll
  for (int nt = 0; nt < 8; ++nt) acc[nt] = (f32x4){0.f, 0.f, 0.f, 0.f};
#pragma unroll
  for (int h = 0; h < 2; ++h) {
    if (h) __syncthreads();
#pragma unroll
    for (int p = 0; p < 16; ++p) {
      const int f = p * 1024 + tid * 4;
      const int o = f >> 7, kk = f & 127;
      float4 v = *(const float4*)(W + o * 256 + h * 128 + kk);
      uint2 pk;
      pk.x = pk2bf(v.x, v.y);
      pk.y = pk2bf(v.z, v.w);
      *(uint2*)(&WF[o >> 4][kk >> 5][((o & 15) + (((kk & 31) >> 3) << 4)) * 8 + (kk & 7)]) = pk;
    }
    __syncthreads();
#pragma unroll
    for (int kl = 0; kl < 4; ++kl) {
      const int kc = h * 4 + kl;
#pragma unroll
      for (int nt = 0; nt < 8; ++nt) {
        B8 bv;
        bv.i4 = *(const int4*)(&WF[nt][kl][lane * 8]);
        acc[nt] = __builtin_amdgcn_mfma_f32_16x16x32_bf16(av[kc].b, bv.b, acc[nt], 0, 0, 0);
      }
    }
  }
  float asrc[8], adst[8];
#pragma unroll
  for (int nt = 0; nt < 8; ++nt) {
    asrc[nt] = a[nt * 16 + il];
    adst[nt] = a[128 + nt * 16 + il];
  }
  float sp[4], dp[4];
#pragma unroll
  for (int r = 0; r < 4; ++r) {
    float sv = 0.f, dv = 0.f;
#pragma unroll
    for (int nt = 0; nt < 8; ++nt) {
      sv += acc[nt][r] * asrc[nt];
      dv += acc[nt][r] * adst[nt];
    }
    sp[r] = sv; dp[r] = dv;
  }
#pragma unroll
  for (int off = 1; off <= 8; off <<= 1) {
#pragma unroll
    for (int r = 0; r < 4; ++r) {
      sp[r] += __shfl_xor(sp[r], off, 64);
      dp[r] += __shfl_xor(dp[r], off, 64);
    }
  }
  if (il == 0) {
#pragma unroll
    for (int r = 0; r < 4; ++r) {
      s_out[row0 + wave * 16 + quad * 4 + r] = sp[r];
      d_out[row0 + wave * 16 + quad * 4 + r] = dp[r];
    }
  }
  const int b = row0 >> 11;
  const int jc = ((row0 & 2047) >> 5) + (wave >> 1);
  const int kin = ((wave & 1) << 4) + (quad << 2);
  const int kq = kin >> 3, u0 = kin & 7;
#pragma unroll
  for (int nt = 0; nt < 8; ++nt) {
    uint2 pk;
    pk.x = pk2bf(acc[nt][0], acc[nt][1]);
    pk.y = pk2bf(acc[nt][2], acc[nt][3]);
    *(uint2*)(whTf + ((((size_t)(b * 64 + jc)) * 8 + nt) << 9) + ((il + (kq << 4)) << 3) + u0) = pk;
  }
}

// ---------------- Kernel B: fused mask+attention, LDS-DMA pipelined MFMA -----------
// 256 blocks (1/CU); b = blk&7 pins batch to one XCD (whTf L2-resident). adj is read
// directly (coalesced 256B row segments + __ballot -> per-lane register mask double
// buffer) -- the pack pass is fused away. Pipeline per chunk-pair T: issue adj loads
// for T+1, DMA V-pair T+1, compute pair T, ballot T+1 (loads covered by compute).
__global__ __launch_bounds__(256) void gat_attn(
    const int* __restrict__ adj, const unsigned short* __restrict__ whTf,
    const float* __restrict__ s, const float* __restrict__ dvec,
    float* __restrict__ out) {
  __shared__ unsigned short vbuf[2][2][8][512];  // 32 KB: [buf][chunk][nt][frag]
  __shared__ float dl[2048];                     // 8 KB (pre-scaled by LOG2E)
  const int tid = threadIdx.x;
  const int wave = tid >> 6;
  const int lane = tid & 63;
  const int il = lane & 15;
  const int quad = lane >> 4;
  const int qo = quad << 3;
  const int b = blockIdx.x & 7;
  const int tile = blockIdx.x >> 3;
  const int rbase = tile * 64;
  {
    const float* dsrc = dvec + ((size_t)b << 11);
#pragma unroll
    for (int it = 0; it < 2; ++it) {
      const int idx = it * 1024 + tid * 4;
      float4 v = *(const float4*)(dsrc + idx);
      v.x *= LOG2E; v.y *= LOG2E; v.z *= LOG2E; v.w *= LOG2E;
      *(float4*)(&dl[idx]) = v;
    }
  }
  // adj base for this wave's 16 rows (each row 8 KB apart; loads are 256B coalesced)
  const int* aro = adj + ((((size_t)b << 11) + rbase + wave * 16) << 11);
  int lv[16];
#pragma unroll
  for (int r = 0; r < 16; ++r) lv[r] = aro[(r << 11) + lane];
  const unsigned short* whTb = whTf + (((size_t)b * 64) << 12);
  {
#pragma unroll
    for (int h = 0; h < 2; ++h) {
      const int nt = wave * 2 + h;
      dma16(whTb + ((size_t)(0 * 8 + nt) << 9) + (lane << 3), &vbuf[0][0][nt][0]);
      dma16(whTb + ((size_t)(1 * 8 + nt) << 9) + (lane << 3), &vbuf[0][1][nt][0]);
    }
  }
  const int i = rbase + wave * 16 + il;
  const size_t browi = ((size_t)b << 11) + i;
  const float svL = s[browi] * LOG2E;
  // prologue ballots -> mcur: lane keeps the 64-bit mask of ITS row (il)
  unsigned long long mcur;
  {
    unsigned long long sel = __ballot(lv[0] != 0);
#pragma unroll
    for (int r = 1; r < 16; ++r) {
      const unsigned long long mm = __ballot(lv[r] != 0);
      sel = (il == r) ? mm : sel;
    }
    mcur = sel;
  }
  f32x4 acc[8];
#pragma unroll
  for (int nt = 0; nt < 8; ++nt) acc[nt] = (f32x4){0.f, 0.f, 0.f, 0.f};
  float den = 0.f;
  __syncthreads();   // drains prologue DMA + dl stores

  for (int T = 0; T < 32; ++T) {
    const int cur = T & 1, nxt = cur ^ 1;
    if (T < 31) {
      // 1. issue adj loads for pair T+1 (independent, 256B coalesced each)
#pragma unroll
      for (int r = 0; r < 16; ++r) lv[r] = aro[(r << 11) + (T + 1) * 64 + lane];
      // 2. DMA next V-chunk-pair
#pragma unroll
      for (int h = 0; h < 2; ++h) {
        const int nt = wave * 2 + h;
        dma16(whTb + (((size_t)(2 * T + 2) * 8 + nt) << 9) + (lane << 3), &vbuf[nxt][0][nt][0]);
        dma16(whTb + (((size_t)(2 * T + 3) * 8 + nt) << 9) + (lane << 3), &vbuf[nxt][1][nt][0]);
      }
    }
    // 3. compute the two chunks of pair T
#pragma unroll
    for (int c = 0; c < 2; ++c) {
      const int j0 = (2 * T + c) * 32;
      const unsigned int mq = (unsigned int)(mcur >> (32 * c + qo));  // bits u=0..7
      const float4 d0 = *(const float4*)(&dl[j0 + qo]);
      const float4 d1 = *(const float4*)(&dl[j0 + qo + 4]);
      const float dd[8] = {d0.x, d0.y, d0.z, d0.w, d1.x, d1.y, d1.z, d1.w};
      B8 af[8];
#pragma unroll
      for (int nt = 0; nt < 8; ++nt)
        af[nt].i4 = *(const int4*)((const char*)&vbuf[cur][c][nt][0] + lane * 16);
      float pv[8];
#pragma unroll
      for (int u = 0; u < 8; ++u) {
        float t0 = svL + dd[u];                       // e * LOG2E
        float e2 = fmaxf(t0, GAT_ALPHA * t0);         // leaky relu (scale-invariant)
        float p = __builtin_amdgcn_exp2f(e2);         // no max-sub: e <= ~18
        p = ((mq >> u) & 1u) ? p : 0.f;
        den += p;
        pv[u] = p;
      }
      B8 pf;
      pf.w[0] = pk2bf(pv[0], pv[1]);
      pf.w[1] = pk2bf(pv[2], pv[3]);
      pf.w[2] = pk2bf(pv[4], pv[5]);
      pf.w[3] = pk2bf(pv[6], pv[7]);
#pragma unroll
      for (int nt = 0; nt < 8; ++nt)
        acc[nt] = __builtin_amdgcn_mfma_f32_16x16x32_bf16(af[nt].b, pf.b, acc[nt], 0, 0, 0);
    }
    // 4. ballots for pair T+1 (adj loads have had the whole compute phase to land)
    if (T < 31) {
      unsigned long long sel = __ballot(lv[0] != 0);
#pragma unroll
      for (int r = 1; r < 16; ++r) {
        const unsigned long long mm = __ballot(lv[r] != 0);
        sel = (il == r) ? mm : sel;
      }
      mcur = sel;
    }
    __syncthreads();  // all waves done with vbuf[cur]; own next-DMA drained
  }
  den += __shfl_xor(den, 16, 64);
  den += __shfl_xor(den, 32, 64);
  const float inv = 1.0f / den;
  float* op = out + browi * 128;
#pragma unroll
  for (int nt = 0; nt < 8; ++nt) {
    float4 v;
    v.x = fmaxf(acc[nt][0] * inv, 0.f);
    v.y = fmaxf(acc[nt][1] * inv, 0.f);
    v.z = fmaxf(acc[nt][2] * inv, 0.f);
    v.w = fmaxf(acc[nt][3] * inv, 0.f);
    *(float4*)(op + nt * 16 + quad * 4) = v;
  }
}

extern "C" void kernel_launch(void* const* d_in, const int* in_sizes, int n_in,
                              void* d_out, int out_size, void* d_ws, size_t ws_size,
                              hipStream_t stream) {
  const float* x = (const float*)d_in[0];
  const int* adj = (const int*)d_in[1];
  const float* W = (const float*)d_in[2];
  const float* a = (const float*)d_in[3];
  float* out = (float*)d_out;
  // ws: whTf bf16 4 MB | s fp32 64 KB | d fp32 64 KB
  unsigned short* whTf = (unsigned short*)d_ws;
  float* s = (float*)((char*)d_ws + (size_t)4 * 1024 * 1024);
  float* dv = s + 16384;
  gat_wh<<<256, 256, 0, stream>>>(x, W, a, whTf, s, dv);
  gat_attn<<<256, 256, 0, stream>>>(adj, whTf, s, dv, out);
}